// Round 11
// baseline (924.528 us; speedup 1.0000x reference)
//
#include <hip/hip_runtime.h>
#include <math.h>

#define N_NODES 131072
#define N_EDGES 524288
#define IN_DIM_ 78
#define HID_ 64
#define HEADS_ 4
#define NG 4096
#define NPG 32
#define NLAYERS 3
#define NEG_SLOPE 0.2f
#define SCAN_BLOCKS 128
#define WF_LSTRIDE 27648   // per-layer Wf stride: 3ch * 18 tiles * 64 lanes * 8

typedef __attribute__((ext_vector_type(8))) short bf16x8;
typedef __attribute__((ext_vector_type(4))) float f32x4;

// bf16 helpers (round-to-nearest-even)
__device__ __forceinline__ unsigned short f2bf(float f) {
    unsigned int u = __float_as_uint(f);
    u = (u + 0x7FFF + ((u >> 16) & 1)) >> 16;
    return (unsigned short)u;
}
__device__ __forceinline__ float bf2f(unsigned short u) {
    return __uint_as_float(((unsigned int)u) << 16);
}

// ---------------- CSR build ----------------

__global__ void init_counts(int* __restrict__ cnt, float* __restrict__ pooled) {
    int n = blockIdx.x * blockDim.x + threadIdx.x;
    if (n < N_NODES) cnt[n] = 1;   // 1 = the self loop
    for (int j = n; j < NG * NLAYERS * 64; j += N_NODES) pooled[j] = 0.f;
}

__global__ void count_edges(const int* __restrict__ dst, int* __restrict__ cnt) {
    int e = blockIdx.x * blockDim.x + threadIdx.x;
    if (e < N_EDGES) atomicAdd(&cnt[dst[e]], 1);
}

// ---- parallel exclusive scan of cnt (131072) + fused self-loop placement ----
__global__ void blocksum(const int* __restrict__ cnt, int* __restrict__ part) {
    __shared__ int red[4];
    int b = blockIdx.x, t = threadIdx.x;
    int4 v = ((const int4*)cnt)[b * 256 + t];
    int s = v.x + v.y + v.z + v.w;
    #pragma unroll
    for (int m = 1; m < 64; m <<= 1) s += __shfl_xor(s, m, 64);
    if ((t & 63) == 0) red[t >> 6] = s;
    __syncthreads();
    if (t == 0) part[b] = red[0] + red[1] + red[2] + red[3];
}

__global__ void scanpart(int* __restrict__ part) {
    __shared__ int sh[SCAN_BLOCKS];
    int t = threadIdx.x;
    int v = part[t];
    sh[t] = v;
    __syncthreads();
    for (int off = 1; off < SCAN_BLOCKS; off <<= 1) {
        int u = (t >= off) ? sh[t - off] : 0;
        __syncthreads();
        sh[t] += u;
        __syncthreads();
    }
    part[t] = sh[t] - v;   // exclusive
}

// offsets + self-loop place + cursor init (cursor aliases cnt; each thread
// reads its own int4 before overwriting those words)
__global__ void scanfinal(const int* __restrict__ cnt, const int* __restrict__ part,
                          int* __restrict__ offsets, int* __restrict__ cursor,
                          int* __restrict__ csr_src) {
    __shared__ int sh[256];
    int b = blockIdx.x, t = threadIdx.x;
    int idx4 = b * 256 + t;
    int4 c = ((const int4*)cnt)[idx4];
    int ts = c.x + c.y + c.z + c.w;
    sh[t] = ts;
    __syncthreads();
    for (int off = 1; off < 256; off <<= 1) {
        int u = (t >= off) ? sh[t - off] : 0;
        __syncthreads();
        sh[t] += u;
        __syncthreads();
    }
    int run = part[b] + sh[t] - ts;
    int n = idx4 * 4;
    int4 o;
    o.x = run; csr_src[run] = n;     cursor[n]     = run + 1; run += c.x;
    o.y = run; csr_src[run] = n + 1; cursor[n + 1] = run + 1; run += c.y;
    o.z = run; csr_src[run] = n + 2; cursor[n + 2] = run + 1; run += c.z;
    o.w = run; csr_src[run] = n + 3; cursor[n + 3] = run + 1; run += c.w;
    ((int4*)offsets)[idx4] = o;
    if (b == SCAN_BLOCKS - 1 && t == 255) offsets[N_NODES] = run;
}

__global__ void scatter_edges(const int* __restrict__ src, const int* __restrict__ dst,
                              int* __restrict__ cursor, int* __restrict__ csr_src) {
    int e = blockIdx.x * blockDim.x + threadIdx.x;
    if (e < N_EDGES) {
        int d = dst[e];
        int pos = atomicAdd(&cursor[d], 1);
        csr_src[pos] = src[e];
    }
}

// ---------------- W prep: split/transpose + aug columns, all 3 layers, 1 kernel ----------------
// Tile t<16: h columns (col = t*16+li). Tiles 16/17: augmented alpha columns
// (W·a_src / W·a_dst per head in li<4, zeros elsewhere).
// Fragment for (layer,ch,t) = 1KB block WfX[l*WF_LSTRIDE + ((ch*18+t)*64+lane)*8 ..].
__global__ void wprep(const float* __restrict__ W0, const float* __restrict__ W1,
                      const float* __restrict__ W2,
                      const float* __restrict__ as0, const float* __restrict__ as1,
                      const float* __restrict__ as2,
                      const float* __restrict__ ad0, const float* __restrict__ ad1,
                      const float* __restrict__ ad2,
                      unsigned short* __restrict__ WfH, unsigned short* __restrict__ WfL) {
    int b = blockIdx.x;              // 0..287 = layer*96 + k
    int l = b / 96, k = b - l * 96;
    const float* W    = (l == 0) ? W0  : (l == 1) ? W1  : W2;
    const float* asrc = (l == 0) ? as0 : (l == 1) ? as1 : as2;
    const float* adst = (l == 0) ? ad0 : (l == 1) ? ad1 : ad2;
    const int K = (l == 0) ? IN_DIM_ : HID_;
    const size_t base = (size_t)l * WF_LSTRIDE;
    const int ch = k >> 5, kk = k & 31;
    const int lg = kk >> 3, j = kk & 7;

    int col = threadIdx.x;
    {
        float w = (k < K) ? W[k * 256 + col] : 0.f;
        unsigned short hi = f2bf(w);
        unsigned short lo = f2bf(w - bf2f(hi));
        int ct = col >> 4, li = col & 15;
        size_t o = base + (((size_t)ch * 18 + ct) * 64 + (lg * 16 + li)) * 8 + j;
        WfH[o] = hi;
        WfL[o] = lo;
    }
    if (col < 32) {
        int tile = 16 + (col >> 4), li = col & 15;
        float v = 0.f;
        if (li < 4 && k < K) {
            const float* a = (tile == 16) ? asrc : adst;
            const float* wr = W + k * 256 + li * 64;
            #pragma unroll 8
            for (int d = 0; d < 64; ++d) v += wr[d] * a[li * 64 + d];
        }
        unsigned short hi = f2bf(v);
        unsigned short lo = f2bf(v - bf2f(hi));
        size_t o = base + (((size_t)ch * 18 + tile) * 64 + (lg * 16 + li)) * 8 + j;
        WfH[o] = hi;
        WfL[o] = lo;
    }
}

// ---------------- MFMA GEMM: zero-shuffle epilogue, alphas as MFMA columns ----------------
// (structure validated r10: gemm dropped below aggregate in the profile)
template<int NCH, int K>
__global__ __launch_bounds__(256)
void gemm_mfma(const float* __restrict__ A,
               const unsigned short* __restrict__ WfH,
               const unsigned short* __restrict__ WfL,
               unsigned short* __restrict__ h, float* __restrict__ als, float* __restrict__ ald) {
    const int tid = threadIdx.x;
    const int w = tid >> 6;
    const int lane = tid & 63;
    const int li = lane & 15, lg = lane >> 4;
    const int row0 = blockIdx.x * 64;
    const int r0 = (w >> 1) * 32;
    const int cw = w & 1;

    // ---- A fragments: global -> registers, split hi/lo ----
    bf16x8 ah[NCH][2], al[NCH][2];
    #pragma unroll
    for (int ch = 0; ch < NCH; ++ch) {
        #pragma unroll
        for (int rt = 0; rt < 2; ++rt) {
            const int row = row0 + r0 + rt * 16 + li;
            const int kb = ch * 32 + lg * 8;
            float t[8];
            if ((ch + 1) * 32 <= K) {
                if constexpr ((K % 4) == 0) {
                    const float4* ap = (const float4*)(A + (size_t)row * K + kb);
                    float4 v0 = ap[0], v1 = ap[1];
                    t[0] = v0.x; t[1] = v0.y; t[2] = v0.z; t[3] = v0.w;
                    t[4] = v1.x; t[5] = v1.y; t[6] = v1.z; t[7] = v1.w;
                } else {
                    const float2* ap = (const float2*)(A + (size_t)row * K + kb);
                    #pragma unroll
                    for (int j = 0; j < 4; ++j) {
                        float2 v = ap[j];
                        t[2 * j] = v.x; t[2 * j + 1] = v.y;
                    }
                }
            } else {
                const float2* ap = (const float2*)(A + (size_t)row * K + kb);
                #pragma unroll
                for (int j = 0; j < 4; ++j) {   // K even -> pairs never straddle
                    float2 v = (kb + 2 * j + 1 < K) ? ap[j] : make_float2(0.f, 0.f);
                    t[2 * j] = v.x; t[2 * j + 1] = v.y;
                }
            }
            bf16x8 hh, ll;
            #pragma unroll
            for (int j = 0; j < 8; ++j) {
                unsigned short hi = f2bf(t[j]);
                unsigned short lo = f2bf(t[j] - bf2f(hi));
                hh[j] = (short)hi; ll[j] = (short)lo;
            }
            ah[ch][rt] = hh; al[ch][rt] = ll;
        }
    }

    f32x4 acc[2][9];
    #pragma unroll
    for (int rt = 0; rt < 2; ++rt)
        #pragma unroll
        for (int ci = 0; ci < 9; ++ci)
            acc[rt][ci] = (f32x4){0.f, 0.f, 0.f, 0.f};

    // ---- main loop: coalesced B fragment loads + 6 MFMA per (ch, tile) ----
    #pragma unroll
    for (int ch = 0; ch < NCH; ++ch) {
        #pragma unroll
        for (int ci = 0; ci < 9; ++ci) {
            const int t = (ci < 8) ? (cw * 8 + ci) : (16 + cw);
            const size_t fo = (((size_t)ch * 18 + t) * 64 + lane) * 8;
            bf16x8 bh = *(const bf16x8*)&WfH[fo];
            bf16x8 bl = *(const bf16x8*)&WfL[fo];
            acc[0][ci] = __builtin_amdgcn_mfma_f32_16x16x32_bf16(ah[ch][0], bh, acc[0][ci], 0, 0, 0);
            acc[1][ci] = __builtin_amdgcn_mfma_f32_16x16x32_bf16(ah[ch][1], bh, acc[1][ci], 0, 0, 0);
            acc[0][ci] = __builtin_amdgcn_mfma_f32_16x16x32_bf16(al[ch][0], bh, acc[0][ci], 0, 0, 0);
            acc[1][ci] = __builtin_amdgcn_mfma_f32_16x16x32_bf16(al[ch][1], bh, acc[1][ci], 0, 0, 0);
            acc[0][ci] = __builtin_amdgcn_mfma_f32_16x16x32_bf16(ah[ch][0], bl, acc[0][ci], 0, 0, 0);
            acc[1][ci] = __builtin_amdgcn_mfma_f32_16x16x32_bf16(ah[ch][1], bl, acc[1][ci], 0, 0, 0);
        }
    }

    // ---- epilogue (zero shuffles): D layout col=li, row=lg*4+reg ----
    #pragma unroll
    for (int rt = 0; rt < 2; ++rt) {
        #pragma unroll
        for (int ci = 0; ci < 8; ++ci) {
            #pragma unroll
            for (int reg = 0; reg < 4; ++reg) {
                int row = row0 + r0 + rt * 16 + lg * 4 + reg;
                int col = cw * 128 + ci * 16 + li;
                h[(size_t)row * 256 + col] = f2bf(acc[rt][ci][reg]);
            }
        }
    }
    float* __restrict__ tgt = cw ? ald : als;
    #pragma unroll
    for (int rt = 0; rt < 2; ++rt) {
        #pragma unroll
        for (int reg = 0; reg < 4; ++reg) {
            int row = row0 + r0 + rt * 16 + lg * 4 + reg;
            if (li < 4) tgt[row * 4 + li] = acc[rt][8][reg];
        }
    }
}

// ---------------- per-node softmax aggregation + fused graph pooling ----------------
__device__ __forceinline__ float pick4(float4 v, int idx) {
    float r = v.x;
    r = (idx == 1) ? v.y : r;
    r = (idx == 2) ? v.z : r;
    r = (idx == 3) ? v.w : r;
    return r;
}

__global__ __launch_bounds__(256)
void aggregate(const int* __restrict__ offsets, const int* __restrict__ csr_src,
               const unsigned short* __restrict__ h, const float* __restrict__ als,
               const float* __restrict__ ald, const float* __restrict__ bias,
               float* __restrict__ hout, float* __restrict__ pooled, int layer) {
    const int lane = threadIdx.x & 63;
    const int wid = __builtin_amdgcn_readfirstlane(threadIdx.x >> 6);
    const int n = blockIdx.x * 4 + wid;
    const int head = lane >> 4;
    const int d4 = (lane & 15) * 4;

    const int o0 = __builtin_amdgcn_readfirstlane(offsets[n]);
    const int o1 = __builtin_amdgcn_readfirstlane(offsets[n + 1]);

    const float ad_h = pick4(*(const float4*)&ald[n * 4], head);

    float4 acc = make_float4(0.f, 0.f, 0.f, 0.f);
    float den = 0.f;

    int i = o0;
    for (; i + 4 <= o1; i += 4) {
        int s0 = __builtin_amdgcn_readfirstlane(csr_src[i + 0]);
        int s1 = __builtin_amdgcn_readfirstlane(csr_src[i + 1]);
        int s2 = __builtin_amdgcn_readfirstlane(csr_src[i + 2]);
        int s3 = __builtin_amdgcn_readfirstlane(csr_src[i + 3]);
        float4 as0 = *(const float4*)&als[s0 * 4];
        float4 as1 = *(const float4*)&als[s1 * 4];
        float4 as2 = *(const float4*)&als[s2 * 4];
        float4 as3 = *(const float4*)&als[s3 * 4];
        ushort4 u0 = ((const ushort4*)h)[(unsigned)(s0 * 64 + lane)];
        ushort4 u1 = ((const ushort4*)h)[(unsigned)(s1 * 64 + lane)];
        ushort4 u2 = ((const ushort4*)h)[(unsigned)(s2 * 64 + lane)];
        ushort4 u3 = ((const ushort4*)h)[(unsigned)(s3 * 64 + lane)];
        float e0 = pick4(as0, head) + ad_h; e0 = e0 > 0.f ? e0 : NEG_SLOPE * e0;
        float e1 = pick4(as1, head) + ad_h; e1 = e1 > 0.f ? e1 : NEG_SLOPE * e1;
        float e2 = pick4(as2, head) + ad_h; e2 = e2 > 0.f ? e2 : NEG_SLOPE * e2;
        float e3 = pick4(as3, head) + ad_h; e3 = e3 > 0.f ? e3 : NEG_SLOPE * e3;
        float p0 = __expf(e0), p1 = __expf(e1), p2 = __expf(e2), p3 = __expf(e3);
        den += p0 + p1 + p2 + p3;
        acc.x += p0 * bf2f(u0.x) + p1 * bf2f(u1.x) + p2 * bf2f(u2.x) + p3 * bf2f(u3.x);
        acc.y += p0 * bf2f(u0.y) + p1 * bf2f(u1.y) + p2 * bf2f(u2.y) + p3 * bf2f(u3.y);
        acc.z += p0 * bf2f(u0.z) + p1 * bf2f(u1.z) + p2 * bf2f(u2.z) + p3 * bf2f(u3.z);
        acc.w += p0 * bf2f(u0.w) + p1 * bf2f(u1.w) + p2 * bf2f(u2.w) + p3 * bf2f(u3.w);
    }
    for (; i < o1; ++i) {
        int s = __builtin_amdgcn_readfirstlane(csr_src[i]);
        float4 asv = *(const float4*)&als[s * 4];
        ushort4 uv = ((const ushort4*)h)[(unsigned)(s * 64 + lane)];
        float e = pick4(asv, head) + ad_h;
        e = e > 0.f ? e : NEG_SLOPE * e;
        float p = __expf(e);
        den += p;
        acc.x += p * bf2f(uv.x); acc.y += p * bf2f(uv.y);
        acc.z += p * bf2f(uv.z); acc.w += p * bf2f(uv.w);
    }

    const float rden = 1.f / den;
    float c0 = acc.x * rden, c1 = acc.y * rden, c2 = acc.z * rden, c3 = acc.w * rden;
    c0 += __shfl_xor(c0, 16, 64); c0 += __shfl_xor(c0, 32, 64);
    c1 += __shfl_xor(c1, 16, 64); c1 += __shfl_xor(c1, 32, 64);
    c2 += __shfl_xor(c2, 16, 64); c2 += __shfl_xor(c2, 32, 64);
    c3 += __shfl_xor(c3, 16, 64); c3 += __shfl_xor(c3, 32, 64);

    if (lane < 16) {
        float4 bv = *(const float4*)&bias[d4];
        float v0 = 0.25f * c0 + bv.x;
        float v1 = 0.25f * c1 + bv.y;
        float v2 = 0.25f * c2 + bv.z;
        float v3 = 0.25f * c3 + bv.w;
        float4 o;
        o.x = v0 > 0.f ? v0 : 0.f;
        o.y = v1 > 0.f ? v1 : 0.f;
        o.z = v2 > 0.f ? v2 : 0.f;
        o.w = v3 > 0.f ? v3 : 0.f;
        *(float4*)&hout[(size_t)n * 64 + d4] = o;
        // fused global_add_pool
        float* pp = &pooled[((n >> 5) * NLAYERS + layer) * 64 + d4];
        atomicAdd(pp + 0, o.x);
        atomicAdd(pp + 1, o.y);
        atomicAdd(pp + 2, o.z);
        atomicAdd(pp + 3, o.w);
    }
}

// ---------------- final layer-attention ----------------
__global__ __launch_bounds__(256)
void final_kernel(const float* __restrict__ pooled, const float* __restrict__ pw,
                  const float* __restrict__ pb, float* __restrict__ out) {
    const int wid = threadIdx.x >> 6, lane = threadIdx.x & 63;
    const int g = blockIdx.x * 4 + wid;
    float v0 = pooled[(g * 3 + 0) * 64 + lane];
    float v1 = pooled[(g * 3 + 1) * 64 + lane];
    float v2 = pooled[(g * 3 + 2) * 64 + lane];
    float w = pw[lane];
    float l0 = v0 * w, l1 = v1 * w, l2 = v2 * w;
    #pragma unroll
    for (int m = 1; m < 64; m <<= 1) {
        l0 += __shfl_xor(l0, m, 64);
        l1 += __shfl_xor(l1, m, 64);
        l2 += __shfl_xor(l2, m, 64);
    }
    float bb = pb[0];
    l0 += bb; l1 += bb; l2 += bb;
    float mx = fmaxf(l0, fmaxf(l1, l2));
    float e0 = __expf(l0 - mx), e1 = __expf(l1 - mx), e2 = __expf(l2 - mx);
    float inv = 1.f / (e0 + e1 + e2);
    out[(size_t)g * 64 + lane] = (v0 * e0 + v1 * e1 + v2 * e2) * inv;
}

// ---------------- launch ----------------
extern "C" void kernel_launch(void* const* d_in, const int* in_sizes, int n_in,
                              void* d_out, int out_size, void* d_ws, size_t ws_size,
                              hipStream_t stream) {
    const float* x  = (const float*)d_in[0];
    const int*   ei = (const int*)d_in[1];
    const float* W[3]    = {(const float*)d_in[3], (const float*)d_in[7],  (const float*)d_in[11]};
    const float* asrc[3] = {(const float*)d_in[4], (const float*)d_in[8],  (const float*)d_in[12]};
    const float* adst[3] = {(const float*)d_in[5], (const float*)d_in[9],  (const float*)d_in[13]};
    const float* bias[3] = {(const float*)d_in[6], (const float*)d_in[10], (const float*)d_in[14]};
    const float* pw = (const float*)d_in[15];
    const float* pb = (const float*)d_in[16];
    float* out = (float*)d_out;

    char* ws = (char*)d_ws;
    size_t off = 0;
    auto alloc = [&](size_t bytes) -> void* {
        void* p = ws + off;
        off = (off + bytes + 255) & ~(size_t)255;
        return p;
    };
    int*   offsets = (int*)alloc((N_NODES + 1) * 4);
    int*   cursor  = (int*)alloc(N_NODES * 4);                 // doubles as cnt
    int*   csr_src = (int*)alloc((size_t)(N_EDGES + N_NODES) * 4);
    int*   part    = (int*)alloc(SCAN_BLOCKS * 4);
    unsigned short* h = (unsigned short*)alloc((size_t)N_NODES * 256 * 2);  // 67 MB bf16
    float* als     = (float*)alloc((size_t)N_NODES * 4 * 4);
    float* ald     = (float*)alloc((size_t)N_NODES * 4 * 4);
    float* hbuf0   = (float*)alloc((size_t)N_NODES * 64 * 4);
    float* hbuf1   = (float*)alloc((size_t)N_NODES * 64 * 4);
    float* pooled  = (float*)alloc((size_t)NG * NLAYERS * 64 * 4);
    unsigned short* WfH = (unsigned short*)alloc((size_t)NLAYERS * WF_LSTRIDE * 2);
    unsigned short* WfL = (unsigned short*)alloc((size_t)NLAYERS * WF_LSTRIDE * 2);
    (void)ws_size; (void)in_sizes; (void)n_in; (void)out_size;

    const int* srcp = ei;
    const int* dstp = ei + N_EDGES;

    init_counts<<<N_NODES / 256, 256, 0, stream>>>(cursor, pooled);
    count_edges<<<N_EDGES / 256, 256, 0, stream>>>(dstp, cursor);
    blocksum<<<SCAN_BLOCKS, 256, 0, stream>>>(cursor, part);
    scanpart<<<1, SCAN_BLOCKS, 0, stream>>>(part);
    scanfinal<<<SCAN_BLOCKS, 256, 0, stream>>>(cursor, part, offsets, cursor, csr_src);
    scatter_edges<<<N_EDGES / 256, 256, 0, stream>>>(srcp, dstp, cursor, csr_src);
    wprep<<<NLAYERS * 96, 256, 0, stream>>>(W[0], W[1], W[2],
                                            asrc[0], asrc[1], asrc[2],
                                            adst[0], adst[1], adst[2], WfH, WfL);

    const float* in = x;
    for (int l = 0; l < 3; ++l) {
        const unsigned short* wfh = WfH + (size_t)l * WF_LSTRIDE;
        const unsigned short* wfl = WfL + (size_t)l * WF_LSTRIDE;
        if (l == 0)
            gemm_mfma<3, IN_DIM_><<<N_NODES / 64, 256, 0, stream>>>(in, wfh, wfl, h, als, ald);
        else
            gemm_mfma<2, HID_><<<N_NODES / 64, 256, 0, stream>>>(in, wfh, wfl, h, als, ald);
        float* ho = (l & 1) ? hbuf1 : hbuf0;
        aggregate<<<N_NODES / 4, 256, 0, stream>>>(offsets, csr_src, h, als, ald, bias[l],
                                                   ho, pooled, l);
        in = ho;
    }
    final_kernel<<<NG / 4, 256, 0, stream>>>(pooled, pw, pb, out);
}

// Round 12
// 469.705 us; speedup vs baseline: 1.9683x; 1.9683x over previous
//
#include <hip/hip_runtime.h>
#include <math.h>

#define N_NODES 131072
#define N_EDGES 524288
#define IN_DIM_ 78
#define HID_ 64
#define HEADS_ 4
#define NG 4096
#define NPG 32
#define NLAYERS 3
#define NEG_SLOPE 0.2f
#define SCAN_BLOCKS 128
#define WF_LSTRIDE 27648   // per-layer Wf stride: 3ch * 18 tiles * 64 lanes * 8

typedef __attribute__((ext_vector_type(8))) short bf16x8;
typedef __attribute__((ext_vector_type(4))) float f32x4;

// bf16 helpers (round-to-nearest-even)
__device__ __forceinline__ unsigned short f2bf(float f) {
    unsigned int u = __float_as_uint(f);
    u = (u + 0x7FFF + ((u >> 16) & 1)) >> 16;
    return (unsigned short)u;
}
__device__ __forceinline__ float bf2f(unsigned short u) {
    return __uint_as_float(((unsigned int)u) << 16);
}

// ---------------- CSR build ----------------

__global__ void init_counts(int* __restrict__ cnt) {
    int n = blockIdx.x * blockDim.x + threadIdx.x;
    if (n < N_NODES) cnt[n] = 1;   // 1 = the self loop
}

__global__ void count_edges(const int* __restrict__ dst, int* __restrict__ cnt) {
    int e = blockIdx.x * blockDim.x + threadIdx.x;
    if (e < N_EDGES) atomicAdd(&cnt[dst[e]], 1);
}

// ---- parallel exclusive scan of cnt (131072) + fused self-loop placement ----
__global__ void blocksum(const int* __restrict__ cnt, int* __restrict__ part) {
    __shared__ int red[4];
    int b = blockIdx.x, t = threadIdx.x;
    int4 v = ((const int4*)cnt)[b * 256 + t];
    int s = v.x + v.y + v.z + v.w;
    #pragma unroll
    for (int m = 1; m < 64; m <<= 1) s += __shfl_xor(s, m, 64);
    if ((t & 63) == 0) red[t >> 6] = s;
    __syncthreads();
    if (t == 0) part[b] = red[0] + red[1] + red[2] + red[3];
}

__global__ void scanpart(int* __restrict__ part) {
    __shared__ int sh[SCAN_BLOCKS];
    int t = threadIdx.x;
    int v = part[t];
    sh[t] = v;
    __syncthreads();
    for (int off = 1; off < SCAN_BLOCKS; off <<= 1) {
        int u = (t >= off) ? sh[t - off] : 0;
        __syncthreads();
        sh[t] += u;
        __syncthreads();
    }
    part[t] = sh[t] - v;   // exclusive
}

// offsets + self-loop place + cursor init (cursor aliases cnt; each thread
// reads its own int4 before overwriting those words)
__global__ void scanfinal(const int* __restrict__ cnt, const int* __restrict__ part,
                          int* __restrict__ offsets, int* __restrict__ cursor,
                          int* __restrict__ csr_src) {
    __shared__ int sh[256];
    int b = blockIdx.x, t = threadIdx.x;
    int idx4 = b * 256 + t;
    int4 c = ((const int4*)cnt)[idx4];
    int ts = c.x + c.y + c.z + c.w;
    sh[t] = ts;
    __syncthreads();
    for (int off = 1; off < 256; off <<= 1) {
        int u = (t >= off) ? sh[t - off] : 0;
        __syncthreads();
        sh[t] += u;
        __syncthreads();
    }
    int run = part[b] + sh[t] - ts;
    int n = idx4 * 4;
    int4 o;
    o.x = run; csr_src[run] = n;     cursor[n]     = run + 1; run += c.x;
    o.y = run; csr_src[run] = n + 1; cursor[n + 1] = run + 1; run += c.y;
    o.z = run; csr_src[run] = n + 2; cursor[n + 2] = run + 1; run += c.z;
    o.w = run; csr_src[run] = n + 3; cursor[n + 3] = run + 1; run += c.w;
    ((int4*)offsets)[idx4] = o;
    if (b == SCAN_BLOCKS - 1 && t == 255) offsets[N_NODES] = run;
}

__global__ void scatter_edges(const int* __restrict__ src, const int* __restrict__ dst,
                              int* __restrict__ cursor, int* __restrict__ csr_src) {
    int e = blockIdx.x * blockDim.x + threadIdx.x;
    if (e < N_EDGES) {
        int d = dst[e];
        int pos = atomicAdd(&cursor[d], 1);
        csr_src[pos] = src[e];
    }
}

// ---------------- W prep: split/transpose + aug columns, all 3 layers, 1 kernel ----------------
// Tile t<16: h columns (col = t*16+li). Tiles 16/17: augmented alpha columns
// (W·a_src / W·a_dst per head in li<4, zeros elsewhere).
// Fragment for (layer,ch,t) = 1KB block WfX[l*WF_LSTRIDE + ((ch*18+t)*64+lane)*8 ..].
__global__ void wprep(const float* __restrict__ W0, const float* __restrict__ W1,
                      const float* __restrict__ W2,
                      const float* __restrict__ as0, const float* __restrict__ as1,
                      const float* __restrict__ as2,
                      const float* __restrict__ ad0, const float* __restrict__ ad1,
                      const float* __restrict__ ad2,
                      unsigned short* __restrict__ WfH, unsigned short* __restrict__ WfL) {
    int b = blockIdx.x;              // 0..287 = layer*96 + k
    int l = b / 96, k = b - l * 96;
    const float* W    = (l == 0) ? W0  : (l == 1) ? W1  : W2;
    const float* asrc = (l == 0) ? as0 : (l == 1) ? as1 : as2;
    const float* adst = (l == 0) ? ad0 : (l == 1) ? ad1 : ad2;
    const int K = (l == 0) ? IN_DIM_ : HID_;
    const size_t base = (size_t)l * WF_LSTRIDE;
    const int ch = k >> 5, kk = k & 31;
    const int lg = kk >> 3, j = kk & 7;

    int col = threadIdx.x;
    {
        float w = (k < K) ? W[k * 256 + col] : 0.f;
        unsigned short hi = f2bf(w);
        unsigned short lo = f2bf(w - bf2f(hi));
        int ct = col >> 4, li = col & 15;
        size_t o = base + (((size_t)ch * 18 + ct) * 64 + (lg * 16 + li)) * 8 + j;
        WfH[o] = hi;
        WfL[o] = lo;
    }
    if (col < 32) {
        int tile = 16 + (col >> 4), li = col & 15;
        float v = 0.f;
        if (li < 4 && k < K) {
            const float* a = (tile == 16) ? asrc : adst;
            const float* wr = W + k * 256 + li * 64;
            #pragma unroll 8
            for (int d = 0; d < 64; ++d) v += wr[d] * a[li * 64 + d];
        }
        unsigned short hi = f2bf(v);
        unsigned short lo = f2bf(v - bf2f(hi));
        size_t o = base + (((size_t)ch * 18 + tile) * 64 + (lg * 16 + li)) * 8 + j;
        WfH[o] = hi;
        WfL[o] = lo;
    }
}

// ---------------- MFMA GEMM: zero-shuffle epilogue, alphas as MFMA columns ----------------
// (structure validated r10: gemm dropped below aggregate in the profile)
template<int NCH, int K>
__global__ __launch_bounds__(256)
void gemm_mfma(const float* __restrict__ A,
               const unsigned short* __restrict__ WfH,
               const unsigned short* __restrict__ WfL,
               unsigned short* __restrict__ h, float* __restrict__ als, float* __restrict__ ald) {
    const int tid = threadIdx.x;
    const int w = tid >> 6;
    const int lane = tid & 63;
    const int li = lane & 15, lg = lane >> 4;
    const int row0 = blockIdx.x * 64;
    const int r0 = (w >> 1) * 32;
    const int cw = w & 1;

    // ---- A fragments: global -> registers, split hi/lo ----
    bf16x8 ah[NCH][2], al[NCH][2];
    #pragma unroll
    for (int ch = 0; ch < NCH; ++ch) {
        #pragma unroll
        for (int rt = 0; rt < 2; ++rt) {
            const int row = row0 + r0 + rt * 16 + li;
            const int kb = ch * 32 + lg * 8;
            float t[8];
            if ((ch + 1) * 32 <= K) {
                if constexpr ((K % 4) == 0) {
                    const float4* ap = (const float4*)(A + (size_t)row * K + kb);
                    float4 v0 = ap[0], v1 = ap[1];
                    t[0] = v0.x; t[1] = v0.y; t[2] = v0.z; t[3] = v0.w;
                    t[4] = v1.x; t[5] = v1.y; t[6] = v1.z; t[7] = v1.w;
                } else {
                    const float2* ap = (const float2*)(A + (size_t)row * K + kb);
                    #pragma unroll
                    for (int j = 0; j < 4; ++j) {
                        float2 v = ap[j];
                        t[2 * j] = v.x; t[2 * j + 1] = v.y;
                    }
                }
            } else {
                const float2* ap = (const float2*)(A + (size_t)row * K + kb);
                #pragma unroll
                for (int j = 0; j < 4; ++j) {   // K even -> pairs never straddle
                    float2 v = (kb + 2 * j + 1 < K) ? ap[j] : make_float2(0.f, 0.f);
                    t[2 * j] = v.x; t[2 * j + 1] = v.y;
                }
            }
            bf16x8 hh, ll;
            #pragma unroll
            for (int j = 0; j < 8; ++j) {
                unsigned short hi = f2bf(t[j]);
                unsigned short lo = f2bf(t[j] - bf2f(hi));
                hh[j] = (short)hi; ll[j] = (short)lo;
            }
            ah[ch][rt] = hh; al[ch][rt] = ll;
        }
    }

    f32x4 acc[2][9];
    #pragma unroll
    for (int rt = 0; rt < 2; ++rt)
        #pragma unroll
        for (int ci = 0; ci < 9; ++ci)
            acc[rt][ci] = (f32x4){0.f, 0.f, 0.f, 0.f};

    // ---- main loop: coalesced B fragment loads + 6 MFMA per (ch, tile) ----
    #pragma unroll
    for (int ch = 0; ch < NCH; ++ch) {
        #pragma unroll
        for (int ci = 0; ci < 9; ++ci) {
            const int t = (ci < 8) ? (cw * 8 + ci) : (16 + cw);
            const size_t fo = (((size_t)ch * 18 + t) * 64 + lane) * 8;
            bf16x8 bh = *(const bf16x8*)&WfH[fo];
            bf16x8 bl = *(const bf16x8*)&WfL[fo];
            acc[0][ci] = __builtin_amdgcn_mfma_f32_16x16x32_bf16(ah[ch][0], bh, acc[0][ci], 0, 0, 0);
            acc[1][ci] = __builtin_amdgcn_mfma_f32_16x16x32_bf16(ah[ch][1], bh, acc[1][ci], 0, 0, 0);
            acc[0][ci] = __builtin_amdgcn_mfma_f32_16x16x32_bf16(al[ch][0], bh, acc[0][ci], 0, 0, 0);
            acc[1][ci] = __builtin_amdgcn_mfma_f32_16x16x32_bf16(al[ch][1], bh, acc[1][ci], 0, 0, 0);
            acc[0][ci] = __builtin_amdgcn_mfma_f32_16x16x32_bf16(ah[ch][0], bl, acc[0][ci], 0, 0, 0);
            acc[1][ci] = __builtin_amdgcn_mfma_f32_16x16x32_bf16(ah[ch][1], bl, acc[1][ci], 0, 0, 0);
        }
    }

    // ---- epilogue (zero shuffles): D layout col=li, row=lg*4+reg ----
    #pragma unroll
    for (int rt = 0; rt < 2; ++rt) {
        #pragma unroll
        for (int ci = 0; ci < 8; ++ci) {
            #pragma unroll
            for (int reg = 0; reg < 4; ++reg) {
                int row = row0 + r0 + rt * 16 + lg * 4 + reg;
                int col = cw * 128 + ci * 16 + li;
                h[(size_t)row * 256 + col] = f2bf(acc[rt][ci][reg]);
            }
        }
    }
    float* __restrict__ tgt = cw ? ald : als;
    #pragma unroll
    for (int rt = 0; rt < 2; ++rt) {
        #pragma unroll
        for (int reg = 0; reg < 4; ++reg) {
            int row = row0 + r0 + rt * 16 + lg * 4 + reg;
            if (li < 4) tgt[row * 4 + li] = acc[rt][8][reg];
        }
    }
}

// ---------------- per-node softmax-weighted aggregation (r10-proven, no atomics) ----------------
__device__ __forceinline__ float pick4(float4 v, int idx) {
    float r = v.x;
    r = (idx == 1) ? v.y : r;
    r = (idx == 2) ? v.z : r;
    r = (idx == 3) ? v.w : r;
    return r;
}

__global__ __launch_bounds__(256)
void aggregate(const int* __restrict__ offsets, const int* __restrict__ csr_src,
               const unsigned short* __restrict__ h, const float* __restrict__ als,
               const float* __restrict__ ald, const float* __restrict__ bias,
               float* __restrict__ hout) {
    const int lane = threadIdx.x & 63;
    const int wid = __builtin_amdgcn_readfirstlane(threadIdx.x >> 6);
    const int n = blockIdx.x * 4 + wid;
    const int head = lane >> 4;
    const int d4 = (lane & 15) * 4;

    const int o0 = __builtin_amdgcn_readfirstlane(offsets[n]);
    const int o1 = __builtin_amdgcn_readfirstlane(offsets[n + 1]);

    const float ad_h = pick4(*(const float4*)&ald[n * 4], head);

    float4 acc = make_float4(0.f, 0.f, 0.f, 0.f);
    float den = 0.f;

    int i = o0;
    for (; i + 4 <= o1; i += 4) {
        int s0 = __builtin_amdgcn_readfirstlane(csr_src[i + 0]);
        int s1 = __builtin_amdgcn_readfirstlane(csr_src[i + 1]);
        int s2 = __builtin_amdgcn_readfirstlane(csr_src[i + 2]);
        int s3 = __builtin_amdgcn_readfirstlane(csr_src[i + 3]);
        float4 as0 = *(const float4*)&als[s0 * 4];
        float4 as1 = *(const float4*)&als[s1 * 4];
        float4 as2 = *(const float4*)&als[s2 * 4];
        float4 as3 = *(const float4*)&als[s3 * 4];
        ushort4 u0 = ((const ushort4*)(h + (size_t)s0 * 256))[lane];
        ushort4 u1 = ((const ushort4*)(h + (size_t)s1 * 256))[lane];
        ushort4 u2 = ((const ushort4*)(h + (size_t)s2 * 256))[lane];
        ushort4 u3 = ((const ushort4*)(h + (size_t)s3 * 256))[lane];
        float e0 = pick4(as0, head) + ad_h; e0 = e0 > 0.f ? e0 : NEG_SLOPE * e0;
        float e1 = pick4(as1, head) + ad_h; e1 = e1 > 0.f ? e1 : NEG_SLOPE * e1;
        float e2 = pick4(as2, head) + ad_h; e2 = e2 > 0.f ? e2 : NEG_SLOPE * e2;
        float e3 = pick4(as3, head) + ad_h; e3 = e3 > 0.f ? e3 : NEG_SLOPE * e3;
        float p0 = __expf(e0), p1 = __expf(e1), p2 = __expf(e2), p3 = __expf(e3);
        den += p0 + p1 + p2 + p3;
        acc.x += p0 * bf2f(u0.x) + p1 * bf2f(u1.x) + p2 * bf2f(u2.x) + p3 * bf2f(u3.x);
        acc.y += p0 * bf2f(u0.y) + p1 * bf2f(u1.y) + p2 * bf2f(u2.y) + p3 * bf2f(u3.y);
        acc.z += p0 * bf2f(u0.z) + p1 * bf2f(u1.z) + p2 * bf2f(u2.z) + p3 * bf2f(u3.z);
        acc.w += p0 * bf2f(u0.w) + p1 * bf2f(u1.w) + p2 * bf2f(u2.w) + p3 * bf2f(u3.w);
    }
    for (; i < o1; ++i) {
        int s = __builtin_amdgcn_readfirstlane(csr_src[i]);
        float4 asv = *(const float4*)&als[s * 4];
        ushort4 uv = ((const ushort4*)(h + (size_t)s * 256))[lane];
        float e = pick4(asv, head) + ad_h;
        e = e > 0.f ? e : NEG_SLOPE * e;
        float p = __expf(e);
        den += p;
        acc.x += p * bf2f(uv.x); acc.y += p * bf2f(uv.y);
        acc.z += p * bf2f(uv.z); acc.w += p * bf2f(uv.w);
    }

    const float rden = 1.f / den;
    float c0 = acc.x * rden, c1 = acc.y * rden, c2 = acc.z * rden, c3 = acc.w * rden;
    c0 += __shfl_xor(c0, 16, 64); c0 += __shfl_xor(c0, 32, 64);
    c1 += __shfl_xor(c1, 16, 64); c1 += __shfl_xor(c1, 32, 64);
    c2 += __shfl_xor(c2, 16, 64); c2 += __shfl_xor(c2, 32, 64);
    c3 += __shfl_xor(c3, 16, 64); c3 += __shfl_xor(c3, 32, 64);

    if (lane < 16) {
        float4 bv = *(const float4*)&bias[d4];
        float v0 = 0.25f * c0 + bv.x;
        float v1 = 0.25f * c1 + bv.y;
        float v2 = 0.25f * c2 + bv.z;
        float v3 = 0.25f * c3 + bv.w;
        float4 o;
        o.x = v0 > 0.f ? v0 : 0.f;
        o.y = v1 > 0.f ? v1 : 0.f;
        o.z = v2 > 0.f ? v2 : 0.f;
        o.w = v3 > 0.f ? v3 : 0.f;
        *(float4*)&hout[(size_t)n * 64 + d4] = o;
    }
}

// ---------------- per-graph pooling (separate kernel — cheap, atomic-free) ----------------
__global__ __launch_bounds__(256)
void pool_kernel(const float* __restrict__ hout, float* __restrict__ pooled, int layer) {
    const int wid = threadIdx.x >> 6, lane = threadIdx.x & 63;
    const int g = blockIdx.x * 4 + wid;
    float s = 0.f;
    const float* p = &hout[(size_t)g * NPG * 64 + lane];
    #pragma unroll 8
    for (int i = 0; i < NPG; ++i) s += p[i * 64];
    pooled[(g * NLAYERS + layer) * 64 + lane] = s;
}

// ---------------- final layer-attention ----------------
__global__ __launch_bounds__(256)
void final_kernel(const float* __restrict__ pooled, const float* __restrict__ pw,
                  const float* __restrict__ pb, float* __restrict__ out) {
    const int wid = threadIdx.x >> 6, lane = threadIdx.x & 63;
    const int g = blockIdx.x * 4 + wid;
    float v0 = pooled[(g * 3 + 0) * 64 + lane];
    float v1 = pooled[(g * 3 + 1) * 64 + lane];
    float v2 = pooled[(g * 3 + 2) * 64 + lane];
    float w = pw[lane];
    float l0 = v0 * w, l1 = v1 * w, l2 = v2 * w;
    #pragma unroll
    for (int m = 1; m < 64; m <<= 1) {
        l0 += __shfl_xor(l0, m, 64);
        l1 += __shfl_xor(l1, m, 64);
        l2 += __shfl_xor(l2, m, 64);
    }
    float bb = pb[0];
    l0 += bb; l1 += bb; l2 += bb;
    float mx = fmaxf(l0, fmaxf(l1, l2));
    float e0 = __expf(l0 - mx), e1 = __expf(l1 - mx), e2 = __expf(l2 - mx);
    float inv = 1.f / (e0 + e1 + e2);
    out[(size_t)g * 64 + lane] = (v0 * e0 + v1 * e1 + v2 * e2) * inv;
}

// ---------------- launch ----------------
extern "C" void kernel_launch(void* const* d_in, const int* in_sizes, int n_in,
                              void* d_out, int out_size, void* d_ws, size_t ws_size,
                              hipStream_t stream) {
    const float* x  = (const float*)d_in[0];
    const int*   ei = (const int*)d_in[1];
    const float* W[3]    = {(const float*)d_in[3], (const float*)d_in[7],  (const float*)d_in[11]};
    const float* asrc[3] = {(const float*)d_in[4], (const float*)d_in[8],  (const float*)d_in[12]};
    const float* adst[3] = {(const float*)d_in[5], (const float*)d_in[9],  (const float*)d_in[13]};
    const float* bias[3] = {(const float*)d_in[6], (const float*)d_in[10], (const float*)d_in[14]};
    const float* pw = (const float*)d_in[15];
    const float* pb = (const float*)d_in[16];
    float* out = (float*)d_out;

    char* ws = (char*)d_ws;
    size_t off = 0;
    auto alloc = [&](size_t bytes) -> void* {
        void* p = ws + off;
        off = (off + bytes + 255) & ~(size_t)255;
        return p;
    };
    int*   offsets = (int*)alloc((N_NODES + 1) * 4);
    int*   cursor  = (int*)alloc(N_NODES * 4);                 // doubles as cnt
    int*   csr_src = (int*)alloc((size_t)(N_EDGES + N_NODES) * 4);
    int*   part    = (int*)alloc(SCAN_BLOCKS * 4);
    unsigned short* h = (unsigned short*)alloc((size_t)N_NODES * 256 * 2);  // 67 MB bf16
    float* als     = (float*)alloc((size_t)N_NODES * 4 * 4);
    float* ald     = (float*)alloc((size_t)N_NODES * 4 * 4);
    float* hbuf0   = (float*)alloc((size_t)N_NODES * 64 * 4);
    float* hbuf1   = (float*)alloc((size_t)N_NODES * 64 * 4);
    float* pooled  = (float*)alloc((size_t)NG * NLAYERS * 64 * 4);
    unsigned short* WfH = (unsigned short*)alloc((size_t)NLAYERS * WF_LSTRIDE * 2);
    unsigned short* WfL = (unsigned short*)alloc((size_t)NLAYERS * WF_LSTRIDE * 2);
    (void)ws_size; (void)in_sizes; (void)n_in; (void)out_size;

    const int* srcp = ei;
    const int* dstp = ei + N_EDGES;

    init_counts<<<N_NODES / 256, 256, 0, stream>>>(cursor);
    count_edges<<<N_EDGES / 256, 256, 0, stream>>>(dstp, cursor);
    blocksum<<<SCAN_BLOCKS, 256, 0, stream>>>(cursor, part);
    scanpart<<<1, SCAN_BLOCKS, 0, stream>>>(part);
    scanfinal<<<SCAN_BLOCKS, 256, 0, stream>>>(cursor, part, offsets, cursor, csr_src);
    scatter_edges<<<N_EDGES / 256, 256, 0, stream>>>(srcp, dstp, cursor, csr_src);
    wprep<<<NLAYERS * 96, 256, 0, stream>>>(W[0], W[1], W[2],
                                            asrc[0], asrc[1], asrc[2],
                                            adst[0], adst[1], adst[2], WfH, WfL);

    const float* in = x;
    for (int l = 0; l < 3; ++l) {
        const unsigned short* wfh = WfH + (size_t)l * WF_LSTRIDE;
        const unsigned short* wfl = WfL + (size_t)l * WF_LSTRIDE;
        if (l == 0)
            gemm_mfma<3, IN_DIM_><<<N_NODES / 64, 256, 0, stream>>>(in, wfh, wfl, h, als, ald);
        else
            gemm_mfma<2, HID_><<<N_NODES / 64, 256, 0, stream>>>(in, wfh, wfl, h, als, ald);
        float* ho = (l & 1) ? hbuf1 : hbuf0;
        aggregate<<<N_NODES / 4, 256, 0, stream>>>(offsets, csr_src, h, als, ald, bias[l], ho);
        pool_kernel<<<NG / 4, 256, 0, stream>>>(ho, pooled, l);
        in = ho;
    }
    final_kernel<<<NG / 4, 256, 0, stream>>>(pooled, pw, pb, out);
}